// Round 6
// baseline (155.952 us; speedup 1.0000x reference)
//
#include <hip/hip_runtime.h>
#include <stdint.h>

#define NUM_ACT 6
#define NUM_OPP 3
#define NUM_SAMPLE 80
#define BATCH 4096
#define DIM 512
#define ACC_STRIDE 98304   /* BATCH*24 */
#define TROWS 64

// ---------------- JAX threefry2x32 (key = (0, 42)) ----------------
__device__ __forceinline__ uint32_t rotl32(uint32_t x, int d) {
  return (x << d) | (x >> (32 - d));
}

__device__ __forceinline__ void tf_round4(uint32_t& x0, uint32_t& x1,
                                          int r0, int r1, int r2, int r3) {
  x0 += x1; x1 = rotl32(x1, r0); x1 ^= x0;
  x0 += x1; x1 = rotl32(x1, r1); x1 ^= x0;
  x0 += x1; x1 = rotl32(x1, r2); x1 ^= x0;
  x0 += x1; x1 = rotl32(x1, r3); x1 ^= x0;
}

__device__ __forceinline__ void threefry2x32(uint32_t k0, uint32_t k1,
                                             uint32_t& x0, uint32_t& x1) {
  const uint32_t ks2 = k0 ^ k1 ^ 0x1BD11BDAu;
  x0 += k0;  x1 += k1;
  tf_round4(x0, x1, 13, 15, 26, 6);  x0 += k1;  x1 += ks2 + 1u;
  tf_round4(x0, x1, 17, 29, 16, 24); x0 += ks2; x1 += k0  + 2u;
  tf_round4(x0, x1, 13, 15, 26, 6);  x0 += k0;  x1 += k1  + 3u;
  tf_round4(x0, x1, 17, 29, 16, 24); x0 += k1;  x1 += ks2 + 4u;
  tf_round4(x0, x1, 13, 15, 26, 6);  x0 += ks2; x1 += k0  + 5u;
}

__device__ __forceinline__ float jax_uniform(uint32_t flat_idx) {
  uint32_t x0 = 0u, x1 = flat_idx;
  threefry2x32(0u, 42u, x0, x1);
  uint32_t bits = x0 ^ x1;
  return __uint_as_float((bits >> 9) | 0x3f800000u) - 1.0f;   // [0,1)
}

__device__ __forceinline__ void dot4(float& a, float4 u, float4 v) {
  a = fmaf(u.x, v.x, a); a = fmaf(u.y, v.y, a);
  a = fmaf(u.z, v.z, a); a = fmaf(u.w, v.w, a);
}

// ---------------- K1: split-K tiled GEMM, 4x3 register tile ----------------
// Rows interleaved by 16 (rowg+16j): row stride XSTR=WIDTH+4 -> bank step 4,
// 8 distinct addresses per ds_read_b128 across banks {0,4,..,28}, 8-lane
// broadcast each => conflict-free. NO device fences (R3: 126us regression).
template<int NCH>
__global__ __launch_bounds__(128) void k1_gemm(
    const float* __restrict__ x, const float* __restrict__ Wopp,
    const float* __restrict__ W, float* __restrict__ part,
    float* __restrict__ ent_slots) {
  constexpr int WIDTH = 512 / NCH;                // 64 (nch=8)
  constexpr int XSTR = WIDTH + 4;
  const int tile = blockIdx.x / NCH;              // 0..63
  const int ch = blockIdx.x % NCH;
  const int rowbase = tile * TROWS;
  const int dbase = ch * WIDTH;
  __shared__ float xs[TROWS * XSTR];
  __shared__ float wt[24 * XSTR];
  const int t = threadIdx.x;

  // stage x tile: TROWS x WIDTH floats, coalesced float4
  for (int f = t; f < TROWS * (WIDTH / 4); f += 128) {
    int row = f / (WIDTH / 4), c4 = (f % (WIDTH / 4)) << 2;
    float4 v = *(const float4*)(x + (size_t)(rowbase + row) * DIM + dbase + c4);
    *(float4*)(xs + row * XSTR + c4) = v;
  }
  // stage W chunk transposed: wt[c][dd]
  for (int i = t; i < 24 * WIDTH; i += 128) {
    int c = i % 24, dd = i / 24;
    int d = dbase + dd;
    float v = (c < 18) ? Wopp[(c / 6) * (DIM * 6) + d * 6 + (c % 6)]
                       : W[d * 6 + (c - 18)];
    wt[c * XSTR + dd] = v;
  }
  __syncthreads();

  const int rowg = t >> 3, colg = t & 7;          // 16 x 8
  float acc[4][3];
#pragma unroll
  for (int j = 0; j < 4; j++)
#pragma unroll
    for (int cc = 0; cc < 3; cc++) acc[j][cc] = 0.f;
  const float* xp = xs + rowg * XSTR;             // + 16j*XSTR per sub-row
  const float* wp = wt + (colg * 3) * XSTR;
#pragma unroll 4
  for (int dd = 0; dd < WIDTH; dd += 4) {
    float4 w0 = *(const float4*)(wp + dd);
    float4 w1 = *(const float4*)(wp + XSTR + dd);
    float4 w2 = *(const float4*)(wp + 2 * XSTR + dd);
#pragma unroll
    for (int j = 0; j < 4; j++) {
      float4 xv = *(const float4*)(xp + (16 * j) * XSTR + dd);
      dot4(acc[j][0], xv, w0); dot4(acc[j][1], xv, w1); dot4(acc[j][2], xv, w2);
    }
  }
  float* p = part + (size_t)ch * ACC_STRIDE;
#pragma unroll
  for (int j = 0; j < 4; j++) {
    int r = rowbase + rowg + 16 * j;
#pragma unroll
    for (int cc = 0; cc < 3; cc++)
      p[r * 24 + colg * 3 + cc] = acc[j][cc];
  }
  if (blockIdx.x == 0 && t < 64) ent_slots[t] = 0.f;  // visible at kernel boundary
}

// ---------------- K3: wave-per-row fused tail ----------------
// wave w of block handles batch row b = blockIdx*4+w. Phase A results live in
// registers, broadcast via __shfl; only act/prob cross lanes through per-wave
// LDS (guarded by the 2 block barriers). No fences.
template<int NCH>
__global__ __launch_bounds__(256) void k3_fused(
    const float* __restrict__ part, const float* __restrict__ bopp,
    const float* __restrict__ W, const float* __restrict__ bias,
    float* __restrict__ ent_slots, float* __restrict__ dout) {
  const int t = threadIdx.x;
  const int w = t >> 6, lane = t & 63;
  const int b = blockIdx.x * 4 + w;
  __shared__ float s_W2[108];                     // W rows 512..529 (18x6)
  __shared__ int   s_act[4][NUM_OPP * NUM_SAMPLE];
  __shared__ float s_prob[4][NUM_OPP * NUM_SAMPLE];

  if (t < 108) s_W2[t] = W[DIM * NUM_ACT + t];

  float p[NUM_ACT];
#pragma unroll
  for (int a = 0; a < NUM_ACT; a++) p[a] = 0.f;
  float xw_r = 0.f;

  if (lane < 3) {
    const int k = lane;
    float l[NUM_ACT];
#pragma unroll
    for (int a = 0; a < NUM_ACT; a++) {
      float s = bopp[k * 6 + a];
#pragma unroll
      for (int ch = 0; ch < NCH; ch++)
        s += part[ch * ACC_STRIDE + b * 24 + k * 6 + a];
      l[a] = s;
    }
    float m = l[0];
#pragma unroll
    for (int a = 1; a < NUM_ACT; a++) m = fmaxf(m, l[a]);
    float e[NUM_ACT], Z = 0.f;
#pragma unroll
    for (int a = 0; a < NUM_ACT; a++) { e[a] = expf(l[a] - m); Z += e[a]; }
    float logZ = logf(Z);
    float H = 0.f;
#pragma unroll
    for (int a = 0; a < NUM_ACT; a++) {
      float pa = e[a] / Z;
      p[a] = pa;
      dout[BATCH * NUM_ACT + (k * BATCH + b) * NUM_ACT + a] = pa;
      H -= pa * ((l[a] - m) - logZ);
    }
    atomicAdd(&ent_slots[b & 63], H);
  } else if (lane >= 8 && lane < 8 + NUM_ACT) {
    int a = lane - 8;
    float s = bias[a];
#pragma unroll
    for (int ch = 0; ch < NCH; ch++)
      s += part[ch * ACC_STRIDE + b * 24 + 18 + a];
    xw_r = s;
  }
  __syncthreads();

  // ---- Sampling: 240 samples over 64 lanes (4 each), 1 threefry + CDF ----
#pragma unroll
  for (int j = 0; j < 4; j++) {
    int sid = lane + 64 * j;                      // (k*80+s) flat
    if (sid < NUM_OPP * NUM_SAMPLE) {
      int k = sid / NUM_SAMPLE;
      float u = jax_uniform((uint32_t)sid * BATCH + (uint32_t)b);
      float d[NUM_ACT];
#pragma unroll
      for (int a = 0; a < NUM_ACT; a++) d[a] = __shfl(p[a], k);
      float c = d[0], pr = d[0];
      int sel = 0;
#pragma unroll
      for (int a = 1; a < NUM_ACT; a++) {
        bool take = (u >= c);
        sel += take ? 1 : 0;
        pr = take ? d[a] : pr;
        c += d[a];
      }
      s_act[w][sid] = sel;
      s_prob[w][sid] = pr;
    }
  }
  __syncthreads();

  // ---- Tail: per-wave, shuffle reductions ----
  float p1a = s_prob[w][lane] * s_prob[w][80 + lane] * s_prob[w][160 + lane];
  const bool hasb = lane < (NUM_SAMPLE - 64);
  float p1b = 0.f;
  if (hasb) p1b = s_prob[w][lane + 64] * s_prob[w][144 + lane] * s_prob[w][224 + lane];
  float tot = p1a + p1b;
#pragma unroll
  for (int m = 32; m > 0; m >>= 1) tot += __shfl_xor(tot, m);

  float xwv[NUM_ACT];
#pragma unroll
  for (int a = 0; a < NUM_ACT; a++) xwv[a] = __shfl(xw_r, 8 + a);

  float o[NUM_ACT];
#pragma unroll
  for (int a = 0; a < NUM_ACT; a++) o[a] = 0.f;
  {
    int a0 = s_act[w][lane], a1 = s_act[w][80 + lane], a2 = s_act[w][160 + lane];
    float la[NUM_ACT];
#pragma unroll
    for (int a = 0; a < NUM_ACT; a++)
      la[a] = xwv[a] + s_W2[a0 * 6 + a] + s_W2[(6 + a1) * 6 + a] + s_W2[(12 + a2) * 6 + a];
    float m = la[0];
#pragma unroll
    for (int a = 1; a < NUM_ACT; a++) m = fmaxf(m, la[a]);
    float e[NUM_ACT], Z = 0.f;
#pragma unroll
    for (int a = 0; a < NUM_ACT; a++) { e[a] = expf(la[a] - m); Z += e[a]; }
    float wz = (p1a / tot) / Z;
#pragma unroll
    for (int a = 0; a < NUM_ACT; a++) o[a] = wz * e[a];
  }
  if (hasb) {
    int j = lane + 64;
    int a0 = s_act[w][j], a1 = s_act[w][80 + j], a2 = s_act[w][160 + j];
    float la[NUM_ACT];
#pragma unroll
    for (int a = 0; a < NUM_ACT; a++)
      la[a] = xwv[a] + s_W2[a0 * 6 + a] + s_W2[(6 + a1) * 6 + a] + s_W2[(12 + a2) * 6 + a];
    float m = la[0];
#pragma unroll
    for (int a = 1; a < NUM_ACT; a++) m = fmaxf(m, la[a]);
    float e[NUM_ACT], Z = 0.f;
#pragma unroll
    for (int a = 0; a < NUM_ACT; a++) { e[a] = expf(la[a] - m); Z += e[a]; }
    float wz = (p1b / tot) / Z;
#pragma unroll
    for (int a = 0; a < NUM_ACT; a++) o[a] += wz * e[a];
  }
#pragma unroll
  for (int m = 32; m > 0; m >>= 1)
#pragma unroll
    for (int a = 0; a < NUM_ACT; a++) o[a] += __shfl_xor(o[a], m);
  if (lane == 0) {
#pragma unroll
    for (int a = 0; a < NUM_ACT; a++) dout[b * NUM_ACT + a] = o[a];
  }
}

// ---------------- K4: entropy scalar (64 slots -> 1) ----------------
__global__ __launch_bounds__(64) void k4_ent(
    const float* __restrict__ ent_slots, float* __restrict__ dout) {
  float v = ent_slots[threadIdx.x];
#pragma unroll
  for (int m = 32; m > 0; m >>= 1) v += __shfl_xor(v, m);
  if (threadIdx.x == 0)
    dout[BATCH * NUM_ACT + NUM_OPP * BATCH * NUM_ACT] = v * (1.0f / 12288.0f);
}

extern "C" void kernel_launch(void* const* d_in, const int* in_sizes, int n_in,
                              void* d_out, int out_size, void* d_ws, size_t ws_size,
                              hipStream_t stream) {
  const float* x    = (const float*)d_in[0];
  const float* Wopp = (const float*)d_in[1];
  const float* bopp = (const float*)d_in[2];
  const float* W    = (const float*)d_in[3];
  const float* bias = (const float*)d_in[4];
  float* out = (float*)d_out;
  float* part = (float*)d_ws;

  size_t need8 = ((size_t)8 * ACC_STRIDE + 64) * sizeof(float);
  if (ws_size >= need8) {
    float* ent_slots = part + (size_t)8 * ACC_STRIDE;
    k1_gemm<8><<<(BATCH / TROWS) * 8, 128, 0, stream>>>(x, Wopp, W, part, ent_slots);
    k3_fused<8><<<BATCH / 4, 256, 0, stream>>>(part, bopp, W, bias, ent_slots, out);
    k4_ent<<<1, 64, 0, stream>>>(ent_slots, out);
  } else {
    float* ent_slots = part + (size_t)4 * ACC_STRIDE;
    k1_gemm<4><<<(BATCH / TROWS) * 4, 128, 0, stream>>>(x, Wopp, W, part, ent_slots);
    k3_fused<4><<<BATCH / 4, 256, 0, stream>>>(part, bopp, W, bias, ent_slots, out);
    k4_ent<<<1, 64, 0, stream>>>(ent_slots, out);
  }
}

// Round 7
// 89.642 us; speedup vs baseline: 1.7397x; 1.7397x over previous
//
#include <hip/hip_runtime.h>
#include <stdint.h>

#define NUM_ACT 6
#define NUM_OPP 3
#define NUM_SAMPLE 80
#define BATCH 4096
#define DIM 512
#define ACC_STRIDE 98304   /* BATCH*24 */
#define TROWS 32

// ---------------- JAX threefry2x32 (key = (0, 42)) ----------------
__device__ __forceinline__ uint32_t rotl32(uint32_t x, int d) {
  return (x << d) | (x >> (32 - d));
}

__device__ __forceinline__ void tf_round4(uint32_t& x0, uint32_t& x1,
                                          int r0, int r1, int r2, int r3) {
  x0 += x1; x1 = rotl32(x1, r0); x1 ^= x0;
  x0 += x1; x1 = rotl32(x1, r1); x1 ^= x0;
  x0 += x1; x1 = rotl32(x1, r2); x1 ^= x0;
  x0 += x1; x1 = rotl32(x1, r3); x1 ^= x0;
}

__device__ __forceinline__ void threefry2x32(uint32_t k0, uint32_t k1,
                                             uint32_t& x0, uint32_t& x1) {
  const uint32_t ks2 = k0 ^ k1 ^ 0x1BD11BDAu;
  x0 += k0;  x1 += k1;
  tf_round4(x0, x1, 13, 15, 26, 6);  x0 += k1;  x1 += ks2 + 1u;
  tf_round4(x0, x1, 17, 29, 16, 24); x0 += ks2; x1 += k0  + 2u;
  tf_round4(x0, x1, 13, 15, 26, 6);  x0 += k0;  x1 += k1  + 3u;
  tf_round4(x0, x1, 17, 29, 16, 24); x0 += k1;  x1 += ks2 + 4u;
  tf_round4(x0, x1, 13, 15, 26, 6);  x0 += ks2; x1 += k0  + 5u;
}

__device__ __forceinline__ float jax_uniform(uint32_t flat_idx) {
  uint32_t x0 = 0u, x1 = flat_idx;
  threefry2x32(0u, 42u, x0, x1);
  uint32_t bits = x0 ^ x1;
  return __uint_as_float((bits >> 9) | 0x3f800000u) - 1.0f;   // [0,1)
}

__device__ __forceinline__ void dot4(float& a, float4 u, float4 v) {
  a = fmaf(u.x, v.x, a); a = fmaf(u.y, v.y, a);
  a = fmaf(u.z, v.z, a); a = fmaf(u.w, v.w, a);
}

// ---------------- K1: split-K tiled GEMM -> per-chunk partials ----------------
// NO device fences (R3: 126us). NO per-row slot atomics anywhere (R5/R6: the
// 12288 atomicAdds to 64 slots + barrier-drain cost 30-79us).
template<int NCH>
__global__ __launch_bounds__(128) void k1_gemm(
    const float* __restrict__ x, const float* __restrict__ Wopp,
    const float* __restrict__ W, float* __restrict__ part,
    float* __restrict__ ws_ent) {
  constexpr int WIDTH = 512 / NCH;
  constexpr int XSTR = WIDTH + 4;
  const int tile = blockIdx.x / NCH;
  const int ch = blockIdx.x % NCH;
  const int rowbase = tile * TROWS;
  const int dbase = ch * WIDTH;
  __shared__ float xs[TROWS * XSTR];
  __shared__ float wt[24 * XSTR];
  const int t = threadIdx.x;

  for (int f = t; f < TROWS * (WIDTH / 4); f += 128) {
    int row = f / (WIDTH / 4), c4 = (f % (WIDTH / 4)) << 2;
    float4 v = *(const float4*)(x + (size_t)(rowbase + row) * DIM + dbase + c4);
    *(float4*)(xs + row * XSTR + c4) = v;
  }
  for (int i = t; i < 24 * WIDTH; i += 128) {
    int c = i % 24, dd = i / 24;
    int d = dbase + dd;
    float v = (c < 18) ? Wopp[(c / 6) * (DIM * 6) + d * 6 + (c % 6)]
                       : W[d * 6 + (c - 18)];
    wt[c * XSTR + dd] = v;
  }
  __syncthreads();

  const int rowg = t >> 3, colg = t & 7;
  float acc[2][3] = {{0.f, 0.f, 0.f}, {0.f, 0.f, 0.f}};
  const float* xp = xs + (rowg * 2) * XSTR;
  const float* wp = wt + (colg * 3) * XSTR;
#pragma unroll 4
  for (int dd = 0; dd < WIDTH; dd += 4) {
    float4 x0 = *(const float4*)(xp + dd);
    float4 x1 = *(const float4*)(xp + XSTR + dd);
    float4 w0 = *(const float4*)(wp + dd);
    float4 w1 = *(const float4*)(wp + XSTR + dd);
    float4 w2 = *(const float4*)(wp + 2 * XSTR + dd);
    dot4(acc[0][0], x0, w0); dot4(acc[0][1], x0, w1); dot4(acc[0][2], x0, w2);
    dot4(acc[1][0], x1, w0); dot4(acc[1][1], x1, w1); dot4(acc[1][2], x1, w2);
  }
  const int r0 = rowbase + rowg * 2, c0 = colg * 3;
  float* p = part + (size_t)ch * ACC_STRIDE;
#pragma unroll
  for (int rr = 0; rr < 2; rr++)
#pragma unroll
    for (int cc = 0; cc < 3; cc++)
      p[(r0 + rr) * 24 + c0 + cc] = acc[rr][cc];
  if (blockIdx.x == 0 && t == 0) ws_ent[0] = 0.f;  // visible to k2 at kernel boundary
}

// ---------------- K2: softmax -> dist (d_out) + entropy (192 atomics) --------
template<int NCH>
__global__ __launch_bounds__(256) void k2_softmax(
    const float* __restrict__ part, const float* __restrict__ bopp,
    float* __restrict__ dout, float* __restrict__ ws_ent) {
  int row = blockIdx.x * 256 + threadIdx.x;       // 12288 = 3*4096 rows
  int k = row >> 12, b = row & 4095;
  float l[NUM_ACT];
#pragma unroll
  for (int a = 0; a < NUM_ACT; a++) {
    float s = bopp[k * 6 + a];
#pragma unroll
    for (int ch = 0; ch < NCH; ch++)
      s += part[ch * ACC_STRIDE + b * 24 + k * 6 + a];
    l[a] = s;
  }
  float m = l[0];
#pragma unroll
  for (int a = 1; a < NUM_ACT; a++) m = fmaxf(m, l[a]);
  float e[NUM_ACT], Z = 0.f;
#pragma unroll
  for (int a = 0; a < NUM_ACT; a++) { e[a] = expf(l[a] - m); Z += e[a]; }
  float logZ = logf(Z);
  float H = 0.f;
#pragma unroll
  for (int a = 0; a < NUM_ACT; a++) {
    float pa = e[a] / Z;
    dout[BATCH * NUM_ACT + row * NUM_ACT + a] = pa;
    H -= pa * ((l[a] - m) - logZ);
  }
#pragma unroll
  for (int off = 32; off > 0; off >>= 1) H += __shfl_down(H, off);
  if ((threadIdx.x & 63) == 0) atomicAdd(ws_ent, H);  // 192 total, one address
}

// ---------------- K3: CDF sample + p2 + agent softmax + output ----------------
template<int NCH>
__global__ __launch_bounds__(256) void k3_agent(
    const float* __restrict__ part, const float* __restrict__ bopp,
    const float* __restrict__ W, const float* __restrict__ bias,
    const float* __restrict__ ws_ent, float* __restrict__ dout) {
  int b = blockIdx.x;
  int t = threadIdx.x;
  __shared__ float s_dist[NUM_OPP][NUM_ACT];
  __shared__ float s_xw[NUM_ACT];
  __shared__ float s_bias[NUM_ACT];
  __shared__ float s_W2[NUM_OPP * NUM_ACT][NUM_ACT];
  __shared__ int   s_act[NUM_OPP][NUM_SAMPLE];
  __shared__ float s_prob[NUM_OPP][NUM_SAMPLE];
  __shared__ float s_p1[NUM_SAMPLE];
  __shared__ float s_sum;
  __shared__ float s_wq[NUM_SAMPLE][NUM_ACT];
  __shared__ float s_o[8][NUM_ACT];

  // ---- Phase A (one barrier): disjoint thread ranges ----
  if (t < 18) {
    int k = t / 6, a = t - k * 6;
    s_dist[k][a] = dout[BATCH * NUM_ACT + (k * BATCH + b) * NUM_ACT + a];
  } else if (t >= 64 && t < 64 + NUM_ACT) {
    int a = t - 64;
    float s = 0.f;
#pragma unroll
    for (int ch = 0; ch < NCH; ch++)
      s += part[ch * ACC_STRIDE + b * 24 + 18 + a];
    s_xw[a] = s;
    s_bias[a] = bias[a];
  } else if (t >= 128 && t < 128 + 108) {
    int i = t - 128;
    s_W2[i / 6][i % 6] = W[DIM * NUM_ACT + i];
  }
  __syncthreads();

  // ---- Sampling via inverse CDF: 1 threefry per sample ----
  if (t < NUM_OPP * NUM_SAMPLE) {
    int k = t / NUM_SAMPLE, s = t - k * NUM_SAMPLE;
    float u = jax_uniform((uint32_t)(k * NUM_SAMPLE + s) * BATCH + (uint32_t)b);
    float c = s_dist[k][0], pr = s_dist[k][0];
    int sel = 0;
#pragma unroll
    for (int a = 1; a < NUM_ACT; a++) {
      bool take = (u >= c);
      sel += take ? 1 : 0;
      pr = take ? s_dist[k][a] : pr;
      c += s_dist[k][a];
    }
    s_act[k][s] = sel;
    s_prob[k][s] = pr;
  }
  __syncthreads();

  // ---- p1 + sum in one phase (wave 0) ----
  if (t < 64) {
    float v = s_prob[0][t] * s_prob[1][t] * s_prob[2][t];
    s_p1[t] = v;
    if (t < 16) {
      float v2 = s_prob[0][t + 64] * s_prob[1][t + 64] * s_prob[2][t + 64];
      s_p1[t + 64] = v2;
      v += v2;
    }
#pragma unroll
    for (int off = 32; off > 0; off >>= 1) v += __shfl_down(v, off);
    if (t == 0) s_sum = v;
  }
  __syncthreads();

  // ---- per-sample weight + agent softmax ----
  if (t < NUM_SAMPLE) {
    float w = s_p1[t] / s_sum;
    int a0 = s_act[0][t], a1 = s_act[1][t], a2 = s_act[2][t];
    float la[NUM_ACT];
#pragma unroll
    for (int a = 0; a < NUM_ACT; a++)
      la[a] = s_xw[a] + s_W2[a0][a] + s_W2[6 + a1][a] + s_W2[12 + a2][a] + s_bias[a];
    float m = la[0];
#pragma unroll
    for (int a = 1; a < NUM_ACT; a++) m = fmaxf(m, la[a]);
    float e[NUM_ACT], Z = 0.f;
#pragma unroll
    for (int a = 0; a < NUM_ACT; a++) { e[a] = expf(la[a] - m); Z += e[a]; }
    float wz = w / Z;
#pragma unroll
    for (int a = 0; a < NUM_ACT; a++) s_wq[t][a] = wz * e[a];
  }
  __syncthreads();

  // ---- column reduction over 80 samples ----
  if (t < 48) {
    int sc = t / 6, a = t - sc * 6;
    float sm = 0.f;
#pragma unroll
    for (int i = 0; i < 10; i++) sm += s_wq[sc * 10 + i][a];
    s_o[sc][a] = sm;
  }
  __syncthreads();
  if (t < NUM_ACT) {
    float sm = 0.f;
#pragma unroll
    for (int sc = 0; sc < 8; sc++) sm += s_o[sc][t];
    dout[b * NUM_ACT + t] = sm;
  }
  if (b == 0 && t == 255) {
    // ws_ent complete: k2 finished at kernel boundary before k3 started
    dout[BATCH * NUM_ACT + NUM_OPP * BATCH * NUM_ACT] = ws_ent[0] * (1.0f / 12288.0f);
  }
}

extern "C" void kernel_launch(void* const* d_in, const int* in_sizes, int n_in,
                              void* d_out, int out_size, void* d_ws, size_t ws_size,
                              hipStream_t stream) {
  const float* x    = (const float*)d_in[0];
  const float* Wopp = (const float*)d_in[1];
  const float* bopp = (const float*)d_in[2];
  const float* W    = (const float*)d_in[3];
  const float* bias = (const float*)d_in[4];
  float* out = (float*)d_out;
  float* part = (float*)d_ws;

  size_t need8 = ((size_t)8 * ACC_STRIDE + 1) * sizeof(float);
  if (ws_size >= need8) {
    float* ws_ent = part + (size_t)8 * ACC_STRIDE;
    k1_gemm<8><<<(BATCH / TROWS) * 8, 128, 0, stream>>>(x, Wopp, W, part, ws_ent);
    k2_softmax<8><<<48, 256, 0, stream>>>(part, bopp, out, ws_ent);
    k3_agent<8><<<BATCH, 256, 0, stream>>>(part, bopp, W, bias, ws_ent, out);
  } else {
    float* ws_ent = part + (size_t)4 * ACC_STRIDE;
    k1_gemm<4><<<(BATCH / TROWS) * 4, 128, 0, stream>>>(x, Wopp, W, part, ws_ent);
    k2_softmax<4><<<48, 256, 0, stream>>>(part, bopp, out, ws_ent);
    k3_agent<4><<<BATCH, 256, 0, stream>>>(part, bopp, W, bias, ws_ent, out);
  }
}

// Round 8
// 89.526 us; speedup vs baseline: 1.7420x; 1.0013x over previous
//
#include <hip/hip_runtime.h>
#include <stdint.h>

#define NUM_ACT 6
#define NUM_OPP 3
#define NUM_SAMPLE 80
#define BATCH 4096
#define DIM 512
#define ACC_STRIDE 98304   /* BATCH*24 */
#define TROWS 32

// ---------------- JAX threefry2x32 (key = (0, 42)) ----------------
__device__ __forceinline__ uint32_t rotl32(uint32_t x, int d) {
  return (x << d) | (x >> (32 - d));
}

__device__ __forceinline__ void tf_round4(uint32_t& x0, uint32_t& x1,
                                          int r0, int r1, int r2, int r3) {
  x0 += x1; x1 = rotl32(x1, r0); x1 ^= x0;
  x0 += x1; x1 = rotl32(x1, r1); x1 ^= x0;
  x0 += x1; x1 = rotl32(x1, r2); x1 ^= x0;
  x0 += x1; x1 = rotl32(x1, r3); x1 ^= x0;
}

__device__ __forceinline__ void threefry2x32(uint32_t k0, uint32_t k1,
                                             uint32_t& x0, uint32_t& x1) {
  const uint32_t ks2 = k0 ^ k1 ^ 0x1BD11BDAu;
  x0 += k0;  x1 += k1;
  tf_round4(x0, x1, 13, 15, 26, 6);  x0 += k1;  x1 += ks2 + 1u;
  tf_round4(x0, x1, 17, 29, 16, 24); x0 += ks2; x1 += k0  + 2u;
  tf_round4(x0, x1, 13, 15, 26, 6);  x0 += k0;  x1 += k1  + 3u;
  tf_round4(x0, x1, 17, 29, 16, 24); x0 += k1;  x1 += ks2 + 4u;
  tf_round4(x0, x1, 13, 15, 26, 6);  x0 += ks2; x1 += k0  + 5u;
}

__device__ __forceinline__ float jax_uniform(uint32_t flat_idx) {
  uint32_t x0 = 0u, x1 = flat_idx;
  threefry2x32(0u, 42u, x0, x1);
  uint32_t bits = x0 ^ x1;
  return __uint_as_float((bits >> 9) | 0x3f800000u) - 1.0f;   // [0,1)
}

__device__ __forceinline__ void dot4(float& a, float4 u, float4 v) {
  a = fmaf(u.x, v.x, a); a = fmaf(u.y, v.y, a);
  a = fmaf(u.z, v.z, a); a = fmaf(u.w, v.w, a);
}

// ---------------- K1: split-K tiled GEMM -> per-chunk partials ----------------
// NO device fences (R3: 126us). NO contended slot atomics (R5/R6: 30-79us).
template<int NCH>
__global__ __launch_bounds__(128) void k1_gemm(
    const float* __restrict__ x, const float* __restrict__ Wopp,
    const float* __restrict__ W, float* __restrict__ part,
    float* __restrict__ ws_ent) {
  constexpr int WIDTH = 512 / NCH;
  constexpr int XSTR = WIDTH + 4;
  const int tile = blockIdx.x / NCH;
  const int ch = blockIdx.x % NCH;
  const int rowbase = tile * TROWS;
  const int dbase = ch * WIDTH;
  __shared__ float xs[TROWS * XSTR];
  __shared__ float wt[24 * XSTR];
  const int t = threadIdx.x;

  for (int f = t; f < TROWS * (WIDTH / 4); f += 128) {
    int row = f / (WIDTH / 4), c4 = (f % (WIDTH / 4)) << 2;
    float4 v = *(const float4*)(x + (size_t)(rowbase + row) * DIM + dbase + c4);
    *(float4*)(xs + row * XSTR + c4) = v;
  }
  for (int i = t; i < 24 * WIDTH; i += 128) {
    int c = i % 24, dd = i / 24;
    int d = dbase + dd;
    float v = (c < 18) ? Wopp[(c / 6) * (DIM * 6) + d * 6 + (c % 6)]
                       : W[d * 6 + (c - 18)];
    wt[c * XSTR + dd] = v;
  }
  __syncthreads();

  const int rowg = t >> 3, colg = t & 7;
  float acc[2][3] = {{0.f, 0.f, 0.f}, {0.f, 0.f, 0.f}};
  const float* xp = xs + (rowg * 2) * XSTR;
  const float* wp = wt + (colg * 3) * XSTR;
#pragma unroll 4
  for (int dd = 0; dd < WIDTH; dd += 4) {
    float4 x0 = *(const float4*)(xp + dd);
    float4 x1 = *(const float4*)(xp + XSTR + dd);
    float4 w0 = *(const float4*)(wp + dd);
    float4 w1 = *(const float4*)(wp + XSTR + dd);
    float4 w2 = *(const float4*)(wp + 2 * XSTR + dd);
    dot4(acc[0][0], x0, w0); dot4(acc[0][1], x0, w1); dot4(acc[0][2], x0, w2);
    dot4(acc[1][0], x1, w0); dot4(acc[1][1], x1, w1); dot4(acc[1][2], x1, w2);
  }
  const int r0 = rowbase + rowg * 2, c0 = colg * 3;
  float* p = part + (size_t)ch * ACC_STRIDE;
#pragma unroll
  for (int rr = 0; rr < 2; rr++)
#pragma unroll
    for (int cc = 0; cc < 3; cc++)
      p[(r0 + rr) * 24 + c0 + cc] = acc[rr][cc];
  if (blockIdx.x == 0 && t == 0) ws_ent[0] = 0.f;  // visible to k2 at kernel boundary
}

// ---------------- K2: softmax -> dist (d_out) + entropy (192 atomics) --------
template<int NCH>
__global__ __launch_bounds__(256) void k2_softmax(
    const float* __restrict__ part, const float* __restrict__ bopp,
    float* __restrict__ dout, float* __restrict__ ws_ent) {
  int row = blockIdx.x * 256 + threadIdx.x;       // 12288 = 3*4096 rows
  int k = row >> 12, b = row & 4095;
  float l[NUM_ACT];
#pragma unroll
  for (int a = 0; a < NUM_ACT; a++) {
    float s = bopp[k * 6 + a];
#pragma unroll
    for (int ch = 0; ch < NCH; ch++)
      s += part[ch * ACC_STRIDE + b * 24 + k * 6 + a];
    l[a] = s;
  }
  float m = l[0];
#pragma unroll
  for (int a = 1; a < NUM_ACT; a++) m = fmaxf(m, l[a]);
  float e[NUM_ACT], Z = 0.f;
#pragma unroll
  for (int a = 0; a < NUM_ACT; a++) { e[a] = expf(l[a] - m); Z += e[a]; }
  float logZ = logf(Z);
  float H = 0.f;
#pragma unroll
  for (int a = 0; a < NUM_ACT; a++) {
    float pa = e[a] / Z;
    dout[BATCH * NUM_ACT + row * NUM_ACT + a] = pa;
    H -= pa * ((l[a] - m) - logZ);
  }
#pragma unroll
  for (int off = 32; off > 0; off >>= 1) H += __shfl_down(H, off);
  if ((threadIdx.x & 63) == 0) atomicAdd(ws_ent, H);  // end-of-kernel, one address
}

// ---------------- K3: CDF sample + wave-0 shuffle tail ----------------
template<int NCH>
__global__ __launch_bounds__(256) void k3_agent(
    const float* __restrict__ part, const float* __restrict__ bopp,
    const float* __restrict__ W, const float* __restrict__ bias,
    const float* __restrict__ ws_ent, float* __restrict__ dout) {
  int b = blockIdx.x;
  int t = threadIdx.x;
  __shared__ float s_dist[NUM_OPP][NUM_ACT];
  __shared__ float s_xw[NUM_ACT];
  __shared__ float s_bias[NUM_ACT];
  __shared__ float s_W2[NUM_OPP * NUM_ACT][NUM_ACT];
  __shared__ int   s_act[NUM_OPP][NUM_SAMPLE];
  __shared__ float s_prob[NUM_OPP][NUM_SAMPLE];

  // ---- Phase A (one barrier): disjoint thread ranges ----
  if (t < 18) {
    int k = t / 6, a = t - k * 6;
    s_dist[k][a] = dout[BATCH * NUM_ACT + (k * BATCH + b) * NUM_ACT + a];
  } else if (t >= 64 && t < 64 + NUM_ACT) {
    int a = t - 64;
    float s = bias[a];
#pragma unroll
    for (int ch = 0; ch < NCH; ch++)
      s += part[ch * ACC_STRIDE + b * 24 + 18 + a];
    s_xw[a] = s;                                   // xw + bias pre-added
  } else if (t >= 128 && t < 128 + 108) {
    int i = t - 128;
    s_W2[i / 6][i % 6] = W[DIM * NUM_ACT + i];
  }
  __syncthreads();

  // ---- Sampling via inverse CDF: 1 threefry per sample ----
  if (t < NUM_OPP * NUM_SAMPLE) {
    int k = t / NUM_SAMPLE, s = t - k * NUM_SAMPLE;
    float u = jax_uniform((uint32_t)(k * NUM_SAMPLE + s) * BATCH + (uint32_t)b);
    float c = s_dist[k][0], pr = s_dist[k][0];
    int sel = 0;
#pragma unroll
    for (int a = 1; a < NUM_ACT; a++) {
      bool take = (u >= c);
      sel += take ? 1 : 0;
      pr = take ? s_dist[k][a] : pr;
      c += s_dist[k][a];
    }
    s_act[k][s] = sel;
    s_prob[k][s] = pr;
  }
  __syncthreads();

  // ---- Tail: wave 0 only, shuffle reductions, no more barriers ----
  if (t < 64) {
    float p1a = s_prob[0][t] * s_prob[1][t] * s_prob[2][t];
    const bool hasb = t < (NUM_SAMPLE - 64);
    float p1b = 0.f;
    if (hasb) p1b = s_prob[0][t + 16] * s_prob[1][t + 16] * s_prob[2][t + 16];
    // NOTE: careful — sample index for the b-half is t+64:
    if (hasb) p1b = s_prob[0][t + 64] * s_prob[1][t + 64] * s_prob[2][t + 64];
    float tot = p1a + p1b;
#pragma unroll
    for (int m = 32; m > 0; m >>= 1) tot += __shfl_xor(tot, m);

    float o[NUM_ACT];
#pragma unroll
    for (int a = 0; a < NUM_ACT; a++) o[a] = 0.f;
    {
      int a0 = s_act[0][t], a1 = s_act[1][t], a2 = s_act[2][t];
      float la[NUM_ACT];
#pragma unroll
      for (int a = 0; a < NUM_ACT; a++)
        la[a] = s_xw[a] + s_W2[a0][a] + s_W2[6 + a1][a] + s_W2[12 + a2][a];
      float m = la[0];
#pragma unroll
      for (int a = 1; a < NUM_ACT; a++) m = fmaxf(m, la[a]);
      float e[NUM_ACT], Z = 0.f;
#pragma unroll
      for (int a = 0; a < NUM_ACT; a++) { e[a] = expf(la[a] - m); Z += e[a]; }
      float wz = (p1a / tot) / Z;
#pragma unroll
      for (int a = 0; a < NUM_ACT; a++) o[a] = wz * e[a];
    }
    if (hasb) {
      int j = t + 64;
      int a0 = s_act[0][j], a1 = s_act[1][j], a2 = s_act[2][j];
      float la[NUM_ACT];
#pragma unroll
      for (int a = 0; a < NUM_ACT; a++)
        la[a] = s_xw[a] + s_W2[a0][a] + s_W2[6 + a1][a] + s_W2[12 + a2][a];
      float m = la[0];
#pragma unroll
      for (int a = 1; a < NUM_ACT; a++) m = fmaxf(m, la[a]);
      float e[NUM_ACT], Z = 0.f;
#pragma unroll
      for (int a = 0; a < NUM_ACT; a++) { e[a] = expf(la[a] - m); Z += e[a]; }
      float wz = (p1b / tot) / Z;
#pragma unroll
      for (int a = 0; a < NUM_ACT; a++) o[a] += wz * e[a];
    }
#pragma unroll
    for (int m = 32; m > 0; m >>= 1)
#pragma unroll
      for (int a = 0; a < NUM_ACT; a++) o[a] += __shfl_xor(o[a], m);
    if (t == 0) {
#pragma unroll
      for (int a = 0; a < NUM_ACT; a++) dout[b * NUM_ACT + a] = o[a];
    }
  }
  if (b == 0 && t == 255) {
    // ws_ent complete: k2 finished at kernel boundary before k3 started
    dout[BATCH * NUM_ACT + NUM_OPP * BATCH * NUM_ACT] = ws_ent[0] * (1.0f / 12288.0f);
  }
}

extern "C" void kernel_launch(void* const* d_in, const int* in_sizes, int n_in,
                              void* d_out, int out_size, void* d_ws, size_t ws_size,
                              hipStream_t stream) {
  const float* x    = (const float*)d_in[0];
  const float* Wopp = (const float*)d_in[1];
  const float* bopp = (const float*)d_in[2];
  const float* W    = (const float*)d_in[3];
  const float* bias = (const float*)d_in[4];
  float* out = (float*)d_out;
  float* part = (float*)d_ws;

  size_t need8 = ((size_t)8 * ACC_STRIDE + 1) * sizeof(float);
  if (ws_size >= need8) {
    float* ws_ent = part + (size_t)8 * ACC_STRIDE;
    k1_gemm<8><<<(BATCH / TROWS) * 8, 128, 0, stream>>>(x, Wopp, W, part, ws_ent);
    k2_softmax<8><<<48, 256, 0, stream>>>(part, bopp, out, ws_ent);
    k3_agent<8><<<BATCH, 256, 0, stream>>>(part, bopp, W, bias, ws_ent, out);
  } else {
    float* ws_ent = part + (size_t)4 * ACC_STRIDE;
    k1_gemm<4><<<(BATCH / TROWS) * 4, 128, 0, stream>>>(x, Wopp, W, part, ws_ent);
    k2_softmax<4><<<48, 256, 0, stream>>>(part, bopp, out, ws_ent);
    k3_agent<4><<<BATCH, 256, 0, stream>>>(part, bopp, W, bias, ws_ent, out);
  }
}